// Round 1
// baseline (197.050 us; speedup 1.0000x reference)
//
#include <hip/hip_runtime.h>
#include <math.h>
#include <float.h>

// Problem constants (from reference): x is (T,B,C,W,H) = (128,8,32,32,32) f32.
// Per-pixel (b,c,w,h) computation is a pair of linear recurrences over t plus
// running maxes. The drive normalization (y1/max y1) cancels inside the second
// (linear) scan, so one forward pass per pixel suffices.
#define T_STEPS 128
#define NPIX   (8 * 32 * 32 * 32)   // B*C*W*H = 262144 (one t-slice)
#define CHW    (32 * 32 * 32)       // 32768 (param broadcast period)

__global__ __launch_bounds__(256) void divnorm_kernel(
    const float* __restrict__ x,
    const float* __restrict__ tau1,
    const float* __restrict__ tau2,
    const float* __restrict__ sigma,
    const float* __restrict__ nexp,
    const int*   __restrict__ t_sel,
    float* __restrict__ out)
{
    const int pix = blockIdx.x * blockDim.x + threadIdx.x;
    if (pix >= NPIX) return;
    const int chw = pix & (CHW - 1);

    const float a1 = expf(-1.0f / tau1[chw]);
    const float a2 = expf(-1.0f / tau2[chw]);
    const int tc = *t_sel;   // 100; uniform scalar broadcast

    // y1 recurrence: A_t = a1*A_{t-1} + x_t ; Bm_t = a1*(Bm_{t-1} + A_{t-1});
    //   y1[t] = Bm before update (y1[0] = 0).
    // y2' recurrence (un-normalized): c_t = a2*c_{t-1} + y1[t]; y2'[t] = c before update.
    float A = 0.0f, Bm = 0.0f, c2 = 0.0f;
    float m1 = -INFINITY, m2 = -INFINITY;
    float y1c = 0.0f, y2c = 0.0f;

    const float* xp = x + pix;
    #pragma unroll 8
    for (int t = 0; t < T_STEPS; ++t) {
        const float xv = xp[(size_t)t * NPIX];   // coalesced across lanes
        const float y1 = Bm;                     // y1[t]
        const float nA = a1 * A + xv;
        Bm = a1 * (Bm + A);                      // uses old A
        A  = nA;

        const float y2 = c2;                     // y2'[t]
        c2 = a2 * c2 + y1;

        m1 = fmaxf(m1, y1);
        m2 = fmaxf(m2, y2);
        if (t == tc) { y1c = y1; y2c = y2; }
    }

    // drive[tc] = y1[tc]/max_t y1 ; norm[tc] = y2'[tc]/max_t y2'  (M1 cancels)
    const float drive = y1c / m1;
    const float norm  = y2c / m2;
    const float nv    = nexp[chw];
    const float id    = fabsf(powf(drive, nv));
    const float nr    = fabsf(powf(norm,  nv)) + sigma[chw];
    float r = id / nr;
    // jnp.nan_to_num defaults: nan->0, +inf->FLT_MAX, -inf->-FLT_MAX
    if (isnan(r))      r = 0.0f;
    else if (isinf(r)) r = copysignf(FLT_MAX, r);
    out[pix] = r;
}

extern "C" void kernel_launch(void* const* d_in, const int* in_sizes, int n_in,
                              void* d_out, int out_size, void* d_ws, size_t ws_size,
                              hipStream_t stream) {
    const float* x     = (const float*)d_in[0];
    const float* tau1  = (const float*)d_in[1];
    const float* tau2  = (const float*)d_in[2];
    const float* sigma = (const float*)d_in[3];
    const float* nexp  = (const float*)d_in[4];
    const int*   t_sel = (const int*)d_in[5];
    // d_in[6] = t_steps (==128, compile-time constant here)
    float* out = (float*)d_out;

    const int threads = 256;
    const int blocks  = (NPIX + threads - 1) / threads;   // 1024
    divnorm_kernel<<<blocks, threads, 0, stream>>>(x, tau1, tau2, sigma, nexp, t_sel, out);
}